// Round 4
// baseline (8220.074 us; speedup 1.0000x reference)
//
#include <hip/hip_runtime.h>
#include <hip/hip_cooperative_groups.h>

namespace cg = cooperative_groups;

// Problem constants
#define TT   64
#define BB   2048
#define IND  512
#define HH   1024
#define G3   3072
#define TBM  (TT*BB)

typedef short  short8 __attribute__((ext_vector_type(8)));
typedef float  f32x4  __attribute__((ext_vector_type(4)));

__device__ __forceinline__ unsigned short f2bf(float x) {
  unsigned int u = __float_as_uint(x);
  u += 0x7FFFu + ((u >> 16) & 1u);  // RNE
  return (unsigned short)(u >> 16);
}
__device__ __forceinline__ float bf2f(unsigned short u) {
  return __uint_as_float(((unsigned int)u) << 16);
}

// async global->LDS, 16B/lane; LDS dest = wave-uniform base + lane*16
__device__ __forceinline__ void async16(const void* g, void* l) {
  __builtin_amdgcn_global_load_lds(
      (__attribute__((address_space(1))) void*)(void*)g,
      (__attribute__((address_space(3))) void*)l, 16, 0, 0);
}

// ---------------- cast fp32 -> bf16 ----------------
__global__ void cast_bf16_kernel(const float* __restrict__ src,
                                 unsigned short* __restrict__ dst, int n) {
  int stride = gridDim.x * blockDim.x;
  for (int i = blockIdx.x * blockDim.x + threadIdx.x; i * 8 < n; i += stride) {
    int o = i * 8;
    float4 a = *(const float4*)(src + o);
    float4 b = *(const float4*)(src + o + 4);
    ushort4 lo; lo.x = f2bf(a.x); lo.y = f2bf(a.y); lo.z = f2bf(a.z); lo.w = f2bf(a.w);
    ushort4 hi; hi.x = f2bf(b.x); hi.y = f2bf(b.y); hi.z = f2bf(b.z); hi.w = f2bf(b.w);
    *(ushort4*)(dst + o)     = lo;
    *(ushort4*)(dst + o + 4) = hi;
  }
}

__global__ void init_out_kernel(float* __restrict__ out, const float* __restrict__ b3, int n) {
  float v = b3[0];
  for (int i = blockIdx.x * blockDim.x + threadIdx.x; i < n; i += gridDim.x * blockDim.x)
    out[i] = v;
}

// ---------------- bf16 GEMM: C = act(A[M][K] * Bw[N][K]^T + bias) ------------
// 128x128 tile, BK=64, 4 waves (2x2), dbuf LDS, T2 xor-swizzle, T1 XCD swizzle.
template <int RELU>
__global__ __launch_bounds__(256, 2) void gemm_bf16(
    const unsigned short* __restrict__ A,
    const unsigned short* __restrict__ Bw,
    const float* __restrict__ bias,
    unsigned short* __restrict__ C,
    int M, int N, int K) {
  __shared__ __align__(16) unsigned short As[2][128 * 64];
  __shared__ __align__(16) unsigned short Bs[2][128 * 64];
  const int tid = threadIdx.x;
  const int w = tid >> 6, l = tid & 63;
  const int wr = w >> 1, wc = w & 1;
  const int lq = l >> 4, lr = l & 15;
  // XCD-bijective swizzle (nwg % 8 == 0 for all our launches)
  const int gX = gridDim.x;
  int fid = blockIdx.y * gX + blockIdx.x;
  int cpx = (gX * gridDim.y) >> 3;
  int fid2 = (fid & 7) * cpx + (fid >> 3);
  const int  n0 = (fid2 % gX) * 128;
  const long m0 = (long)(fid2 / gX) * 128;
  const int cswz = ((l & 7) ^ (l >> 3)) * 8;          // pre-swizzled source col
  int co[2];                                           // swizzled ds_read col (u16 idx)
#pragma unroll
  for (int kk = 0; kk < 2; kk++)
    co[kk] = (((kk * 64 + lq * 16) ^ ((lr & 7) << 4)) >> 1);

  f32x4 acc[4][4] = {};
  const int NK = K >> 6;

  auto STAGE = [&](int buf, int kb) {
    const int k0 = kb << 6;
#pragma unroll
    for (int j = 0; j < 8; j++) {
      if (w < 2) {
        const int r0 = (w * 8 + j) * 8;
        async16(A + (m0 + r0 + (l >> 3)) * K + k0 + cswz, &As[buf][r0 * 64]);
      } else {
        const int r0 = ((w - 2) * 8 + j) * 8;
        async16(Bw + (long)(n0 + r0 + (l >> 3)) * K + k0 + cswz, &Bs[buf][r0 * 64]);
      }
    }
  };

  STAGE(0, 0);
  for (int kb = 0; kb < NK; kb++) {
    __syncthreads();                       // buf[kb&1] staged; prev reads done
    if (kb + 1 < NK) STAGE((kb + 1) & 1, kb + 1);
    const unsigned short* Ac = As[kb & 1];
    const unsigned short* Bc = Bs[kb & 1];
    short8 af[4][2], bfv[4][2];
#pragma unroll
    for (int mf = 0; mf < 4; mf++) {
      const int row = wr * 64 + mf * 16 + lr;
#pragma unroll
      for (int kk = 0; kk < 2; kk++)
        af[mf][kk] = *(const short8*)&Ac[row * 64 + co[kk]];
    }
#pragma unroll
    for (int nf = 0; nf < 4; nf++) {
      const int row = wc * 64 + nf * 16 + lr;
#pragma unroll
      for (int kk = 0; kk < 2; kk++)
        bfv[nf][kk] = *(const short8*)&Bc[row * 64 + co[kk]];
    }
#pragma unroll
    for (int kk = 0; kk < 2; kk++)
#pragma unroll
      for (int mf = 0; mf < 4; mf++)
#pragma unroll
        for (int nf = 0; nf < 4; nf++)
          acc[mf][nf] = __builtin_amdgcn_mfma_f32_16x16x32_bf16(af[mf][kk], bfv[nf][kk], acc[mf][nf], 0, 0, 0);
  }

#pragma unroll
  for (int nf = 0; nf < 4; nf++) {
    int col = n0 + wc * 64 + nf * 16 + lr;
    float bv = bias[col];
#pragma unroll
    for (int mf = 0; mf < 4; mf++) {
      long row = m0 + wr * 64 + mf * 16 + 4 * lq;
#pragma unroll
      for (int r = 0; r < 4; r++) {
        float v = acc[mf][nf][r] + bv;
        if (RELU) v = fmaxf(v, 0.f);
        C[(row + r) * N + col] = f2bf(v);
      }
    }
  }
}

// ---------------- persistent cooperative GRU (TC steps / launch) -------------
// grid = 256 blocks (16 m-tiles x 16 n-tiles), 512 threads (8 waves, 4x2).
// Per step: gh = h@Whh^T for 3 gates (BM=128 x BN=64 x BK=64, dbuf+swizzle),
// gates + h update + q-dot, grid.sync().
__global__ __launch_bounds__(512, 2) void gru_persist(
    const unsigned short* __restrict__ Whh,  // [3H][H] bf16
    const unsigned short* __restrict__ gx,   // [TC*B][3H] bf16 chunk-local
    const float* __restrict__ bhh,
    const float* __restrict__ W3,
    float* __restrict__ out,                 // [T*B], pre-init b3
    float* __restrict__ hfA, float* __restrict__ hfB,
    unsigned short* __restrict__ hbA, unsigned short* __restrict__ hbB,
    int c, int TC) {
  __shared__ __align__(16) unsigned short As[2][128 * 64];     // 32 KB
  __shared__ __align__(16) unsigned short Bs[2][3][64 * 64];   // 48 KB
  cg::grid_group grid = cg::this_grid();
  const int tid = threadIdx.x;
  const int w = tid >> 6, l = tid & 63;
  const int wr = w >> 1, wc = w & 1;       // 4 row-waves x 2 col-waves
  const int lq = l >> 4, lr = l & 15;
  const int bid = blockIdx.x;
  const int n0 = (bid & 15) * 64;
  const int m0 = (bid >> 4) * 128;
  const int cswz = ((l & 7) ^ (l >> 3)) * 8;
  int co[2];
#pragma unroll
  for (int kk = 0; kk < 2; kk++)
    co[kk] = (((kk * 64 + lq * 16) ^ ((lr & 7) << 4)) >> 1);

  for (int lt = 0; lt < TC; lt++) {
    const int t = c + lt;
    const unsigned short* hpb = (t & 1) ? hbB : hbA;
    const float*          hpf = (t & 1) ? hfB : hfA;
    float*                hnf = (t & 1) ? hfA : hfB;
    unsigned short*       hnb = (t & 1) ? hbA : hbB;

    f32x4 acc[3][2][2] = {};

    auto STAGE = [&](int buf, int kb) {
      const int k0 = kb << 6;
#pragma unroll
      for (int j = 0; j < 5; j++) {
        const int ci = w * 5 + j;
        if (ci < 16) {
          const int r0 = ci * 8;
          async16(hpb + (long)(m0 + r0 + (l >> 3)) * HH + k0 + cswz, &As[buf][r0 * 64]);
        } else {
          const int g = (ci - 16) >> 3, r0 = ((ci - 16) & 7) * 8;
          async16(Whh + (long)(g * HH + n0 + r0 + (l >> 3)) * HH + k0 + cswz,
                  &Bs[buf][g][r0 * 64]);
        }
      }
    };

    STAGE(0, 0);
    for (int kb = 0; kb < 16; kb++) {
      __syncthreads();
      if (kb < 15) STAGE((kb + 1) & 1, kb + 1);
      const unsigned short* Ac = As[kb & 1];
      short8 af[2][2];
#pragma unroll
      for (int mf = 0; mf < 2; mf++) {
        const int row = wr * 32 + mf * 16 + lr;
#pragma unroll
        for (int kk = 0; kk < 2; kk++)
          af[mf][kk] = *(const short8*)&Ac[row * 64 + co[kk]];
      }
#pragma unroll
      for (int g = 0; g < 3; g++) {
        const unsigned short* Bc = Bs[kb & 1][g];
        short8 bfv[2][2];
#pragma unroll
        for (int nf = 0; nf < 2; nf++) {
          const int row = wc * 32 + nf * 16 + lr;
#pragma unroll
          for (int kk = 0; kk < 2; kk++)
            bfv[nf][kk] = *(const short8*)&Bc[row * 64 + co[kk]];
        }
#pragma unroll
        for (int kk = 0; kk < 2; kk++)
#pragma unroll
          for (int mf = 0; mf < 2; mf++)
#pragma unroll
            for (int nf = 0; nf < 2; nf++)
              acc[g][mf][nf] = __builtin_amdgcn_mfma_f32_16x16x32_bf16(af[mf][kk], bfv[nf][kk], acc[g][mf][nf], 0, 0, 0);
      }
    }

    // epilogue: gates, h update, q partials
    float qp[2][4] = {};
#pragma unroll
    for (int nf = 0; nf < 2; nf++) {
      const int n = n0 + wc * 32 + nf * 16 + lr;
      const float bhr = bhh[n], bhz = bhh[HH + n], bhn = bhh[2 * HH + n];
      const float w3v = W3[n];
#pragma unroll
      for (int mf = 0; mf < 2; mf++) {
        const int mrow = m0 + wr * 32 + mf * 16 + 4 * lq;
#pragma unroll
        for (int r = 0; r < 4; r++) {
          const int m = mrow + r;
          const long gxb = ((long)lt * BB + m) * G3 + n;
          float xr = bf2f(gx[gxb]);
          float xz = bf2f(gx[gxb + HH]);
          float xn = bf2f(gx[gxb + 2 * HH]);
          float ghr = acc[0][mf][nf][r] + bhr;
          float ghz = acc[1][mf][nf][r] + bhz;
          float ghn = acc[2][mf][nf][r] + bhn;
          float rg = 1.f / (1.f + __expf(-(xr + ghr)));
          float zg = 1.f / (1.f + __expf(-(xz + ghz)));
          float ng = tanhf(xn + rg * ghn);
          float hp = hpf[(long)m * HH + n];
          float hv = (1.f - zg) * ng + zg * hp;
          hnf[(long)m * HH + n] = hv;
          hnb[(long)m * HH + n] = f2bf(hv);
          qp[mf][r] += hv * w3v;
        }
      }
    }
#pragma unroll
    for (int mf = 0; mf < 2; mf++)
#pragma unroll
      for (int r = 0; r < 4; r++) {
        float v = qp[mf][r];
        v += __shfl_xor(v, 1);
        v += __shfl_xor(v, 2);
        v += __shfl_xor(v, 4);
        v += __shfl_xor(v, 8);
        if (lr == 0) {
          int m = m0 + wr * 32 + mf * 16 + 4 * lq + r;
          atomicAdd(&out[t * BB + m], v);
        }
      }
    __threadfence();
    grid.sync();
  }
}

// ---------------- host ----------------
extern "C" void kernel_launch(void* const* d_in, const int* in_sizes, int n_in,
                              void* d_out, int out_size, void* d_ws, size_t ws_size,
                              hipStream_t stream) {
  const float* inputs = (const float*)d_in[0];
  const float* W1     = (const float*)d_in[1];
  const float* b1     = (const float*)d_in[2];
  const float* W_ih   = (const float*)d_in[3];
  const float* b_ih   = (const float*)d_in[4];
  const float* W_hh   = (const float*)d_in[5];
  const float* b_hh   = (const float*)d_in[6];
  const float* W3     = (const float*)d_in[7];
  const float* b3     = (const float*)d_in[8];
  float* out = (float*)d_out;

  const long FIXED = 38797312L;
  const long PER   = 18874368L;
  int TC = 64;
  while (TC > 1 && FIXED + (long)TC * PER > (long)ws_size) TC >>= 1;

  char* ws = (char*)d_ws;
  unsigned short* whhb = (unsigned short*)ws;
  unsigned short* wihb = whhb + 3145728;
  unsigned short* w1b  = wihb + 3145728;
  float* hf0 = (float*)(ws + 13631488L);
  float* hf1 = hf0 + (long)BB * HH;
  unsigned short* hb0 = (unsigned short*)(ws + 30408704L);
  unsigned short* hb1 = hb0 + (long)BB * HH;
  unsigned short* gxc   = (unsigned short*)(ws + FIXED);
  unsigned short* xc    = gxc + (long)TC * BB * G3;
  unsigned short* inbfc = xc  + (long)TC * BB * HH;

  cast_bf16_kernel<<<512, 256, 0, stream>>>(W1,   w1b,  HH * IND);
  cast_bf16_kernel<<<1024, 256, 0, stream>>>(W_ih, wihb, G3 * HH);
  cast_bf16_kernel<<<1024, 256, 0, stream>>>(W_hh, whhb, G3 * HH);
  hipMemsetAsync(hf0, 0, (long)BB * HH * 4, stream);
  hipMemsetAsync(hb0, 0, (long)BB * HH * 2, stream);
  init_out_kernel<<<512, 256, 0, stream>>>(out, b3, TBM);

  for (int c = 0; c < TT; c += TC) {
    const int rows = TC * BB;
    cast_bf16_kernel<<<2048, 256, 0, stream>>>(
        inputs + (long)c * BB * IND, inbfc, rows * IND);
    gemm_bf16<1><<<dim3(HH / 128, rows / 128), 256, 0, stream>>>(
        inbfc, w1b, b1, xc, rows, HH, IND);
    gemm_bf16<0><<<dim3(G3 / 128, rows / 128), 256, 0, stream>>>(
        xc, wihb, b_ih, gxc, rows, G3, HH);

    const unsigned short* a_whh = whhb;
    const unsigned short* a_gx  = gxc;
    const float* a_bhh = b_hh;
    const float* a_w3  = W3;
    float* a_out = out;
    float* a_hfA = hf0; float* a_hfB = hf1;
    unsigned short* a_hbA = hb0; unsigned short* a_hbB = hb1;
    int a_c = c, a_tc = TC;
    void* args[] = {&a_whh, &a_gx, &a_bhh, &a_w3, &a_out,
                    &a_hfA, &a_hfB, &a_hbA, &a_hbB, &a_c, &a_tc};
    hipLaunchCooperativeKernel(reinterpret_cast<void*>(gru_persist),
                               dim3(256), dim3(512), args, 0, stream);
  }
}

// Round 6
// 3504.630 us; speedup vs baseline: 2.3455x; 2.3455x over previous
//
#include <hip/hip_runtime.h>

// Problem constants
#define TT   64
#define BB   2048
#define IND  512
#define HH   1024
#define G3   3072
#define TBM  (TT*BB)

typedef short  short8 __attribute__((ext_vector_type(8)));
typedef float  f32x4  __attribute__((ext_vector_type(4)));

__device__ __forceinline__ unsigned short f2bf(float x) {
  unsigned int u = __float_as_uint(x);
  u += 0x7FFFu + ((u >> 16) & 1u);  // RNE
  return (unsigned short)(u >> 16);
}
__device__ __forceinline__ float bf2f(unsigned short u) {
  return __uint_as_float(((unsigned int)u) << 16);
}

// async global->LDS, 16B/lane; LDS dest = wave-uniform base + lane*16
__device__ __forceinline__ void async16(const void* g, void* l) {
  __builtin_amdgcn_global_load_lds(
      (__attribute__((address_space(1))) void*)(void*)g,
      (__attribute__((address_space(3))) void*)l, 16, 0, 0);
}

// ---------------- cast fp32 -> bf16 ----------------
__global__ void cast_bf16_kernel(const float* __restrict__ src,
                                 unsigned short* __restrict__ dst, int n) {
  int stride = gridDim.x * blockDim.x;
  for (int i = blockIdx.x * blockDim.x + threadIdx.x; i * 8 < n; i += stride) {
    int o = i * 8;
    float4 a = *(const float4*)(src + o);
    float4 b = *(const float4*)(src + o + 4);
    ushort4 lo; lo.x = f2bf(a.x); lo.y = f2bf(a.y); lo.z = f2bf(a.z); lo.w = f2bf(a.w);
    ushort4 hi; hi.x = f2bf(b.x); hi.y = f2bf(b.y); hi.z = f2bf(b.z); hi.w = f2bf(b.w);
    *(ushort4*)(dst + o)     = lo;
    *(ushort4*)(dst + o + 4) = hi;
  }
}

__global__ void init_out_kernel(float* __restrict__ out, const float* __restrict__ b3, int n) {
  float v = b3[0];
  for (int i = blockIdx.x * blockDim.x + threadIdx.x; i < n; i += gridDim.x * blockDim.x)
    out[i] = v;
}

// ---------------- bf16 GEMM: C = act(A[M][K] * Bw[N][K]^T + bias) ------------
// 128x128 tile, BK=64, 4 waves (2x2), dbuf LDS, T2 xor-swizzle, T1 XCD swizzle.
// (validated R4: passed correctness, SQ_LDS_BANK_CONFLICT = 0)
template <int RELU>
__global__ __launch_bounds__(256, 2) void gemm_bf16(
    const unsigned short* __restrict__ A,
    const unsigned short* __restrict__ Bw,
    const float* __restrict__ bias,
    unsigned short* __restrict__ C,
    int M, int N, int K) {
  __shared__ __align__(16) unsigned short As[2][128 * 64];
  __shared__ __align__(16) unsigned short Bs[2][128 * 64];
  const int tid = threadIdx.x;
  const int w = tid >> 6, l = tid & 63;
  const int wr = w >> 1, wc = w & 1;
  const int lq = l >> 4, lr = l & 15;
  // XCD-bijective swizzle (nwg % 8 == 0 for all our launches)
  const int gX = gridDim.x;
  int fid = blockIdx.y * gX + blockIdx.x;
  int cpx = (gX * gridDim.y) >> 3;
  int fid2 = (fid & 7) * cpx + (fid >> 3);
  const int  n0 = (fid2 % gX) * 128;
  const long m0 = (long)(fid2 / gX) * 128;
  const int cswz = ((l & 7) ^ (l >> 3)) * 8;          // pre-swizzled source col
  int co[2];                                           // swizzled ds_read col
#pragma unroll
  for (int kk = 0; kk < 2; kk++)
    co[kk] = (((kk * 64 + lq * 16) ^ ((lr & 7) << 4)) >> 1);

  f32x4 acc[4][4] = {};
  const int NK = K >> 6;

  auto STAGE = [&](int buf, int kb) {
    const int k0 = kb << 6;
#pragma unroll
    for (int j = 0; j < 8; j++) {
      if (w < 2) {
        const int r0 = (w * 8 + j) * 8;
        async16(A + (m0 + r0 + (l >> 3)) * K + k0 + cswz, &As[buf][r0 * 64]);
      } else {
        const int r0 = ((w - 2) * 8 + j) * 8;
        async16(Bw + (long)(n0 + r0 + (l >> 3)) * K + k0 + cswz, &Bs[buf][r0 * 64]);
      }
    }
  };

  STAGE(0, 0);
  for (int kb = 0; kb < NK; kb++) {
    __syncthreads();
    if (kb + 1 < NK) STAGE((kb + 1) & 1, kb + 1);
    const unsigned short* Ac = As[kb & 1];
    const unsigned short* Bc = Bs[kb & 1];
    short8 af[4][2], bfv[4][2];
#pragma unroll
    for (int mf = 0; mf < 4; mf++) {
      const int row = wr * 64 + mf * 16 + lr;
#pragma unroll
      for (int kk = 0; kk < 2; kk++)
        af[mf][kk] = *(const short8*)&Ac[row * 64 + co[kk]];
    }
#pragma unroll
    for (int nf = 0; nf < 4; nf++) {
      const int row = wc * 64 + nf * 16 + lr;
#pragma unroll
      for (int kk = 0; kk < 2; kk++)
        bfv[nf][kk] = *(const short8*)&Bc[row * 64 + co[kk]];
    }
#pragma unroll
    for (int kk = 0; kk < 2; kk++)
#pragma unroll
      for (int mf = 0; mf < 4; mf++)
#pragma unroll
        for (int nf = 0; nf < 4; nf++)
          acc[mf][nf] = __builtin_amdgcn_mfma_f32_16x16x32_bf16(af[mf][kk], bfv[nf][kk], acc[mf][nf], 0, 0, 0);
  }

#pragma unroll
  for (int nf = 0; nf < 4; nf++) {
    int col = n0 + wc * 64 + nf * 16 + lr;
    float bv = bias[col];
#pragma unroll
    for (int mf = 0; mf < 4; mf++) {
      long row = m0 + wr * 64 + mf * 16 + 4 * lq;
#pragma unroll
      for (int r = 0; r < 4; r++) {
        float v = acc[mf][nf][r] + bv;
        if (RELU) v = fmaxf(v, 0.f);
        C[(row + r) * N + col] = f2bf(v);
      }
    }
  }
}

// ---------------- GRU step (one launch per timestep) -------------------------
// BM=64 x BN=64 x 3 gates, BK=64 dbuf + T2 swizzle, 4 waves (2x2), 2 blocks/CU.
// Launch boundary = the grid barrier (cheap, no cross-XCD L2 flush).
__global__ __launch_bounds__(256, 2) void gru_step(
    const unsigned short* __restrict__ hpb,  // [BB][HH] bf16 h(t-1)
    const float* __restrict__ hpf,           // [BB][HH] f32  h(t-1)
    float* __restrict__ hnf,                 // [BB][HH] f32  h(t)
    unsigned short* __restrict__ hnb,        // [BB][HH] bf16 h(t)
    const unsigned short* __restrict__ Whh,  // [3H][H] bf16
    const unsigned short* __restrict__ gx,   // [TC*B][3H] bf16 chunk-local
    const float* __restrict__ bhh,
    const float* __restrict__ W3,
    float* __restrict__ out,                 // [T*B], pre-init b3
    int lt, int t) {
  __shared__ __align__(16) unsigned short As[2][64 * 64];      // 16 KB
  __shared__ __align__(16) unsigned short Bs[2][3][64 * 64];   // 48 KB
  const int tid = threadIdx.x;
  const int w = tid >> 6, l = tid & 63;
  const int wr = w >> 1, wc = w & 1;
  const int lq = l >> 4, lr = l & 15;
  const int m0 = blockIdx.y * 64;
  const int n0 = blockIdx.x * 64;
  const int cswz = ((l & 7) ^ (l >> 3)) * 8;
  int co[2];
#pragma unroll
  for (int kk = 0; kk < 2; kk++)
    co[kk] = (((kk * 64 + lq * 16) ^ ((lr & 7) << 4)) >> 1);

  f32x4 acc[3][2][2] = {};

  // 32 chunks of 8 rows: 8 for A (64 rows), 24 for B (3 gates x 64 rows); 8/wave
  auto STAGE = [&](int buf, int kb) {
    const int k0 = kb << 6;
#pragma unroll
    for (int j = 0; j < 8; j++) {
      const int ci = w * 8 + j;
      if (ci < 8) {
        const int r0 = ci * 8;
        async16(hpb + (long)(m0 + r0 + (l >> 3)) * HH + k0 + cswz, &As[buf][r0 * 64]);
      } else {
        const int g = (ci - 8) >> 3, r0 = ((ci - 8) & 7) * 8;
        async16(Whh + (long)(g * HH + n0 + r0 + (l >> 3)) * HH + k0 + cswz,
                &Bs[buf][g][r0 * 64]);
      }
    }
  };

  STAGE(0, 0);
  for (int kb = 0; kb < 16; kb++) {
    __syncthreads();
    if (kb < 15) STAGE((kb + 1) & 1, kb + 1);
    const unsigned short* Ac = As[kb & 1];
    short8 af[2][2];
#pragma unroll
    for (int mf = 0; mf < 2; mf++) {
      const int row = wr * 32 + mf * 16 + lr;
#pragma unroll
      for (int kk = 0; kk < 2; kk++)
        af[mf][kk] = *(const short8*)&Ac[row * 64 + co[kk]];
    }
#pragma unroll
    for (int g = 0; g < 3; g++) {
      const unsigned short* Bc = Bs[kb & 1][g];
      short8 bfv[2][2];
#pragma unroll
      for (int nf = 0; nf < 2; nf++) {
        const int row = wc * 32 + nf * 16 + lr;
#pragma unroll
        for (int kk = 0; kk < 2; kk++)
          bfv[nf][kk] = *(const short8*)&Bc[row * 64 + co[kk]];
      }
#pragma unroll
      for (int kk = 0; kk < 2; kk++)
#pragma unroll
        for (int mf = 0; mf < 2; mf++)
#pragma unroll
          for (int nf = 0; nf < 2; nf++)
            acc[g][mf][nf] = __builtin_amdgcn_mfma_f32_16x16x32_bf16(af[mf][kk], bfv[nf][kk], acc[g][mf][nf], 0, 0, 0);
    }
  }

  // epilogue: gates, h update, q partials
  float qp[2][4] = {};
#pragma unroll
  for (int nf = 0; nf < 2; nf++) {
    const int n = n0 + wc * 32 + nf * 16 + lr;
    const float bhr = bhh[n], bhz = bhh[HH + n], bhn = bhh[2 * HH + n];
    const float w3v = W3[n];
#pragma unroll
    for (int mf = 0; mf < 2; mf++) {
      const int mrow = m0 + wr * 32 + mf * 16 + 4 * lq;
#pragma unroll
      for (int r = 0; r < 4; r++) {
        const int m = mrow + r;
        const long gxb = ((long)lt * BB + m) * G3 + n;
        float xr = bf2f(gx[gxb]);
        float xz = bf2f(gx[gxb + HH]);
        float xn = bf2f(gx[gxb + 2 * HH]);
        float ghr = acc[0][mf][nf][r] + bhr;
        float ghz = acc[1][mf][nf][r] + bhz;
        float ghn = acc[2][mf][nf][r] + bhn;
        float rg = 1.f / (1.f + __expf(-(xr + ghr)));
        float zg = 1.f / (1.f + __expf(-(xz + ghz)));
        float ng = tanhf(xn + rg * ghn);
        float hp = hpf[(long)m * HH + n];
        float hv = (1.f - zg) * ng + zg * hp;
        hnf[(long)m * HH + n] = hv;
        hnb[(long)m * HH + n] = f2bf(hv);
        qp[mf][r] += hv * w3v;
      }
    }
  }
#pragma unroll
  for (int mf = 0; mf < 2; mf++)
#pragma unroll
    for (int r = 0; r < 4; r++) {
      float v = qp[mf][r];
      v += __shfl_xor(v, 1);
      v += __shfl_xor(v, 2);
      v += __shfl_xor(v, 4);
      v += __shfl_xor(v, 8);
      if (lr == 0) {
        int m = m0 + wr * 32 + mf * 16 + 4 * lq + r;
        atomicAdd(&out[t * BB + m], v);
      }
    }
}

// ---------------- host ----------------
extern "C" void kernel_launch(void* const* d_in, const int* in_sizes, int n_in,
                              void* d_out, int out_size, void* d_ws, size_t ws_size,
                              hipStream_t stream) {
  const float* inputs = (const float*)d_in[0];
  const float* W1     = (const float*)d_in[1];
  const float* b1     = (const float*)d_in[2];
  const float* W_ih   = (const float*)d_in[3];
  const float* b_ih   = (const float*)d_in[4];
  const float* W_hh   = (const float*)d_in[5];
  const float* b_hh   = (const float*)d_in[6];
  const float* W3     = (const float*)d_in[7];
  const float* b3     = (const float*)d_in[8];
  float* out = (float*)d_out;

  const long FIXED = 38797312L;
  const long PER   = 18874368L;
  int TC = 64;
  while (TC > 1 && FIXED + (long)TC * PER > (long)ws_size) TC >>= 1;

  char* ws = (char*)d_ws;
  unsigned short* whhb = (unsigned short*)ws;
  unsigned short* wihb = whhb + 3145728;
  unsigned short* w1b  = wihb + 3145728;
  float* hf0 = (float*)(ws + 13631488L);
  float* hf1 = hf0 + (long)BB * HH;
  unsigned short* hb0 = (unsigned short*)(ws + 30408704L);
  unsigned short* hb1 = hb0 + (long)BB * HH;
  unsigned short* gxc   = (unsigned short*)(ws + FIXED);
  unsigned short* xc    = gxc + (long)TC * BB * G3;
  unsigned short* inbfc = xc  + (long)TC * BB * HH;

  cast_bf16_kernel<<<512, 256, 0, stream>>>(W1,   w1b,  HH * IND);
  cast_bf16_kernel<<<1024, 256, 0, stream>>>(W_ih, wihb, G3 * HH);
  cast_bf16_kernel<<<1024, 256, 0, stream>>>(W_hh, whhb, G3 * HH);
  hipMemsetAsync(hf0, 0, (long)BB * HH * 4, stream);
  hipMemsetAsync(hb0, 0, (long)BB * HH * 2, stream);
  init_out_kernel<<<512, 256, 0, stream>>>(out, b3, TBM);

  for (int c = 0; c < TT; c += TC) {
    const int rows = TC * BB;
    cast_bf16_kernel<<<2048, 256, 0, stream>>>(
        inputs + (long)c * BB * IND, inbfc, rows * IND);
    gemm_bf16<1><<<dim3(HH / 128, rows / 128), 256, 0, stream>>>(
        inbfc, w1b, b1, xc, rows, HH, IND);
    gemm_bf16<0><<<dim3(G3 / 128, rows / 128), 256, 0, stream>>>(
        xc, wihb, b_ih, gxc, rows, G3, HH);

    for (int lt = 0; lt < TC; lt++) {
      const int t = c + lt;
      const unsigned short* hbr = (t & 1) ? hb1 : hb0;
      const float*          hfr = (t & 1) ? hf1 : hf0;
      float*                hfw = (t & 1) ? hf0 : hf1;
      unsigned short*       hbw = (t & 1) ? hb0 : hb1;
      gru_step<<<dim3(HH / 64, BB / 64), 256, 0, stream>>>(
          hbr, hfr, hfw, hbw, whhb, gxc, b_hh, W3, out, lt, t);
    }
  }
}